// Round 1
// baseline (756.205 us; speedup 1.0000x reference)
//
#include <hip/hip_runtime.h>
#include <math.h>

#define TOKENS 4096
#define EMBD   1024
#define HID    4096
#define NE     8

typedef __attribute__((ext_vector_type(8))) short short8;
typedef __attribute__((ext_vector_type(4))) float f32x4;

#define GLOBAL_PTR(p) ((const __attribute__((address_space(1))) void*)(p))
#define LDS_PTR(p)    ((__attribute__((address_space(3))) void*)(p))

__device__ __forceinline__ unsigned short f2bf(float f) {
  unsigned int u = __float_as_uint(f);
  u += 0x7FFFu + ((u >> 16) & 1u);   // round-to-nearest-even
  return (unsigned short)(u >> 16);
}

// ---------- kernel 1: x fp32 -> bf16, zero control ints ----------
__global__ __launch_bounds__(256) void k_convert_x(const float* __restrict__ x,
                                                   unsigned short* __restrict__ xb,
                                                   int* __restrict__ ctrl) {
  if (blockIdx.x == 0 && threadIdx.x < 32) ctrl[threadIdx.x] = 0;
  int idx = blockIdx.x * 256 + threadIdx.x;
  int stride = gridDim.x * 256;
  const float4* x4 = (const float4*)x;
  ushort4* o4 = (ushort4*)xb;
  for (int i = idx; i < TOKENS * EMBD / 4; i += stride) {
    float4 v = x4[i];
    ushort4 o;
    o.x = f2bf(v.x); o.y = f2bf(v.y); o.z = f2bf(v.z); o.w = f2bf(v.w);
    o4[i] = o;
  }
}

// ---------- transpose+convert: in [e][R][C] fp32 -> out [e][C][R] bf16 ----------
__global__ __launch_bounds__(256) void k_transpose_bf16(const float* __restrict__ in,
                                                        unsigned short* __restrict__ out,
                                                        int R, int C) {
  __shared__ unsigned short tile[64][66];  // 66: conflict-free transpose read
  int e = blockIdx.z;
  const float* ine = in + (size_t)e * R * C;
  unsigned short* oute = out + (size_t)e * R * C;
  int tx = threadIdx.x & 63;
  int ty = threadIdx.x >> 6;   // 0..3
  int r0 = blockIdx.y * 64;
  int c0 = blockIdx.x * 64;
#pragma unroll
  for (int i = 0; i < 16; i++) {
    int r = i * 4 + ty;
    tile[r][tx] = f2bf(ine[(size_t)(r0 + r) * C + c0 + tx]);
  }
  __syncthreads();
#pragma unroll
  for (int i = 0; i < 16; i++) {
    int r = i * 4 + ty;                       // output row within tile = input col
    oute[(size_t)(c0 + r) * R + r0 + tx] = tile[tx][r];
  }
}

// ---------- gating: logits (fp32 exact), top-2, renorm weights; zero out ----------
__global__ __launch_bounds__(256) void k_gate(const float* __restrict__ x,
                                              const float* __restrict__ gw,
                                              float* __restrict__ out,
                                              int* __restrict__ idx2,
                                              float* __restrict__ wv,
                                              int* __restrict__ ctrl) {
  int t = blockIdx.x;
  int tid = threadIdx.x;
  int wave = tid >> 6, lane = tid & 63;
  float acc[NE];
#pragma unroll
  for (int e = 0; e < NE; e++) acc[e] = 0.f;
  const float* xr = x + (size_t)t * EMBD;
  for (int k = tid; k < EMBD; k += 256) {
    float xvv = xr[k];
#pragma unroll
    for (int e = 0; e < NE; e++) acc[e] += xvv * gw[k * NE + e];
  }
#pragma unroll
  for (int e = 0; e < NE; e++) {
#pragma unroll
    for (int off = 32; off > 0; off >>= 1) acc[e] += __shfl_down(acc[e], off);
  }
  __shared__ float part[4][NE];
  if (lane == 0) {
#pragma unroll
    for (int e = 0; e < NE; e++) part[wave][e] = acc[e];
  }
  // zero the output row (poisoned to 0xAA before every launch)
  float4 z = make_float4(0.f, 0.f, 0.f, 0.f);
  ((float4*)out)[t * 256 + tid] = z;
  __syncthreads();
  if (tid == 0) {
    float best = -1e30f, second = -1e30f;
    int bi = 0, si = 0;
#pragma unroll
    for (int e = 0; e < NE; e++) {
      float l = part[0][e] + part[1][e] + part[2][e] + part[3][e];
      if (l > best) { second = best; si = bi; best = l; bi = e; }
      else if (l > second) { second = l; si = e; }
    }
    float b = expf(second - best);
    float w0 = 1.f / (1.f + b);
    float w1 = b / (1.f + b);
    idx2[2 * t] = bi; idx2[2 * t + 1] = si;
    wv[2 * t] = w0; wv[2 * t + 1] = w1;
    atomicAdd(&ctrl[bi], 1);
    atomicAdd(&ctrl[si], 1);
  }
}

// ---------- tiny scan: offsets = exclusive prefix(counts), cursors = 0 ----------
__global__ void k_scan(int* __restrict__ ctrl) {
  if (threadIdx.x == 0) {
    int off = 0;
    for (int e = 0; e < NE; e++) { ctrl[8 + e] = off; off += ctrl[e]; }
    ctrl[16] = off;
  }
  if (threadIdx.x < NE) ctrl[17 + threadIdx.x] = 0;
}

// ---------- slot assignment ----------
__global__ __launch_bounds__(256) void k_assign(const int* __restrict__ idx2,
                                                const float* __restrict__ wv,
                                                int* __restrict__ ctrl,
                                                int* __restrict__ token_list,
                                                float* __restrict__ slot_w) {
  int t = blockIdx.x * 256 + threadIdx.x;
  if (t >= TOKENS) return;
#pragma unroll
  for (int k = 0; k < 2; k++) {
    int e = idx2[2 * t + k];
    int pos = atomicAdd(&ctrl[17 + e], 1);
    int slot = ctrl[8 + e] + pos;
    token_list[slot] = t;
    slot_w[slot] = wv[2 * t + k];
  }
}

// ---------- GEMM1: H = gelu(gather(x) @ w1[e] + b1[e]) ----------
// A: gathered x_bf16 [cnt][1024]; B: w1t [e][4096][1024] (n-major, k-contig)
__global__ __launch_bounds__(256, 2) void k_gemm1(
    const unsigned short* __restrict__ xb,
    const unsigned short* __restrict__ w1t,
    const float* __restrict__ b1,
    const int* __restrict__ ctrl,
    const int* __restrict__ token_list,
    unsigned short* __restrict__ Hbuf) {
  int e = blockIdx.z;
  int cnt = ctrl[e];
  int m_base = blockIdx.y * 128;
  if (m_base >= cnt) return;
  int off_e = ctrl[8 + e];
  int nb = blockIdx.x * 128;
  int tid = threadIdx.x;
  int wave = tid >> 6, lane = tid & 63;

  __shared__ __align__(16) unsigned short As[128 * 32];
  __shared__ __align__(16) unsigned short Bs[128 * 32];

  // staging assignment: lane-load q covers 16B = 8 bf16; row = q>>2, chunk = q&3
  int q0 = tid, q1 = 256 + tid;
  int rowA0 = q0 >> 2, ch0 = q0 & 3;
  int rowA1 = q1 >> 2, ch1 = q1 & 3;
  int tok0 = token_list[off_e + min(m_base + rowA0, cnt - 1)];
  int tok1 = token_list[off_e + min(m_base + rowA1, cnt - 1)];
  const unsigned short* srcA0 = xb + (size_t)tok0 * EMBD + ch0 * 8;
  const unsigned short* srcA1 = xb + (size_t)tok1 * EMBD + ch1 * 8;
  const unsigned short* wb = w1t + (size_t)e * HID * EMBD;
  const unsigned short* srcB0 = wb + (size_t)(nb + rowA0) * EMBD + ch0 * 8;
  const unsigned short* srcB1 = wb + (size_t)(nb + rowA1) * EMBD + ch1 * 8;
  char* AsB = (char*)As;
  char* BsB = (char*)Bs;

  f32x4 acc[4][4];
#pragma unroll
  for (int i = 0; i < 4; i++)
#pragma unroll
    for (int j = 0; j < 4; j++) acc[i][j] = (f32x4){0.f, 0.f, 0.f, 0.f};

  int wm = (wave >> 1) * 64, wn = (wave & 1) * 64;
  int q4 = lane >> 4, cc = lane & 15;

  for (int k0 = 0; k0 < EMBD; k0 += 32) {
    __builtin_amdgcn_global_load_lds(GLOBAL_PTR(srcA0 + k0), LDS_PTR(AsB + wave * 1024), 16, 0, 0);
    __builtin_amdgcn_global_load_lds(GLOBAL_PTR(srcA1 + k0), LDS_PTR(AsB + 4096 + wave * 1024), 16, 0, 0);
    __builtin_amdgcn_global_load_lds(GLOBAL_PTR(srcB0 + k0), LDS_PTR(BsB + wave * 1024), 16, 0, 0);
    __builtin_amdgcn_global_load_lds(GLOBAL_PTR(srcB1 + k0), LDS_PTR(BsB + 4096 + wave * 1024), 16, 0, 0);
    __syncthreads();
    short8 af[4], bfr[4];
#pragma unroll
    for (int i = 0; i < 4; i++)
      af[i] = *(const short8*)(As + (wm + i * 16 + cc) * 32 + q4 * 8);
#pragma unroll
    for (int j = 0; j < 4; j++)
      bfr[j] = *(const short8*)(Bs + (wn + j * 16 + cc) * 32 + q4 * 8);
#pragma unroll
    for (int i = 0; i < 4; i++)
#pragma unroll
      for (int j = 0; j < 4; j++)
        acc[i][j] = __builtin_amdgcn_mfma_f32_16x16x32_bf16(af[i], bfr[j], acc[i][j], 0, 0, 0);
    __syncthreads();
  }

  const float* b1e = b1 + (size_t)e * HID;
  float bias[4];
#pragma unroll
  for (int j = 0; j < 4; j++) bias[j] = b1e[nb + wn + j * 16 + cc];
#pragma unroll
  for (int i = 0; i < 4; i++) {
#pragma unroll
    for (int r = 0; r < 4; r++) {
      int m_loc = wm + i * 16 + q4 * 4 + r;
      int m = m_base + m_loc;
      if (m < cnt) {
        size_t hrow = (size_t)(off_e + m) * HID;
#pragma unroll
        for (int j = 0; j < 4; j++) {
          float v = acc[i][j][r] + bias[j];
          float g = 0.5f * v * (1.f + erff(v * 0.70710678118654752f));
          Hbuf[hrow + nb + wn + j * 16 + cc] = f2bf(g);
        }
      }
    }
  }
}

// ---------- GEMM2: out[token] += w * (H @ w2[e] + b2[e]) ----------
__global__ __launch_bounds__(256, 2) void k_gemm2(
    const unsigned short* __restrict__ Hbuf,
    const unsigned short* __restrict__ w2t,
    const float* __restrict__ b2,
    const int* __restrict__ ctrl,
    const int* __restrict__ token_list,
    const float* __restrict__ slot_w,
    float* __restrict__ out) {
  int e = blockIdx.z;
  int cnt = ctrl[e];
  int m_base = blockIdx.y * 128;
  if (m_base >= cnt) return;
  int off_e = ctrl[8 + e];
  int nb = blockIdx.x * 128;
  int tid = threadIdx.x;
  int wave = tid >> 6, lane = tid & 63;

  __shared__ __align__(16) unsigned short As[128 * 32];
  __shared__ __align__(16) unsigned short Bs[128 * 32];

  int q0 = tid, q1 = 256 + tid;
  int rowA0 = q0 >> 2, ch0 = q0 & 3;
  int rowA1 = q1 >> 2, ch1 = q1 & 3;
  const unsigned short* srcA0 = Hbuf + (size_t)(off_e + m_base + rowA0) * HID + ch0 * 8;
  const unsigned short* srcA1 = Hbuf + (size_t)(off_e + m_base + rowA1) * HID + ch1 * 8;
  const unsigned short* wb = w2t + (size_t)e * EMBD * HID;
  const unsigned short* srcB0 = wb + (size_t)(nb + rowA0) * HID + ch0 * 8;
  const unsigned short* srcB1 = wb + (size_t)(nb + rowA1) * HID + ch1 * 8;
  char* AsB = (char*)As;
  char* BsB = (char*)Bs;

  f32x4 acc[4][4];
#pragma unroll
  for (int i = 0; i < 4; i++)
#pragma unroll
    for (int j = 0; j < 4; j++) acc[i][j] = (f32x4){0.f, 0.f, 0.f, 0.f};

  int wm = (wave >> 1) * 64, wn = (wave & 1) * 64;
  int q4 = lane >> 4, cc = lane & 15;

  for (int k0 = 0; k0 < HID; k0 += 32) {
    __builtin_amdgcn_global_load_lds(GLOBAL_PTR(srcA0 + k0), LDS_PTR(AsB + wave * 1024), 16, 0, 0);
    __builtin_amdgcn_global_load_lds(GLOBAL_PTR(srcA1 + k0), LDS_PTR(AsB + 4096 + wave * 1024), 16, 0, 0);
    __builtin_amdgcn_global_load_lds(GLOBAL_PTR(srcB0 + k0), LDS_PTR(BsB + wave * 1024), 16, 0, 0);
    __builtin_amdgcn_global_load_lds(GLOBAL_PTR(srcB1 + k0), LDS_PTR(BsB + 4096 + wave * 1024), 16, 0, 0);
    __syncthreads();
    short8 af[4], bfr[4];
#pragma unroll
    for (int i = 0; i < 4; i++)
      af[i] = *(const short8*)(As + (wm + i * 16 + cc) * 32 + q4 * 8);
#pragma unroll
    for (int j = 0; j < 4; j++)
      bfr[j] = *(const short8*)(Bs + (wn + j * 16 + cc) * 32 + q4 * 8);
#pragma unroll
    for (int i = 0; i < 4; i++)
#pragma unroll
      for (int j = 0; j < 4; j++)
        acc[i][j] = __builtin_amdgcn_mfma_f32_16x16x32_bf16(af[i], bfr[j], acc[i][j], 0, 0, 0);
    __syncthreads();
  }

  const float* b2e = b2 + (size_t)e * EMBD;
  float bias[4];
#pragma unroll
  for (int j = 0; j < 4; j++) bias[j] = b2e[nb + wn + j * 16 + cc];
#pragma unroll
  for (int i = 0; i < 4; i++) {
#pragma unroll
    for (int r = 0; r < 4; r++) {
      int m_loc = wm + i * 16 + q4 * 4 + r;
      int m = m_base + m_loc;
      if (m < cnt) {
        int slot = off_e + m;
        int tok = token_list[slot];
        float w = slot_w[slot];
        float* orow = out + (size_t)tok * EMBD;
#pragma unroll
        for (int j = 0; j < 4; j++) {
          float v = acc[i][j][r] + bias[j];
          atomicAdd(&orow[nb + wn + j * 16 + cc], w * v);
        }
      }
    }
  }
}

extern "C" void kernel_launch(void* const* d_in, const int* in_sizes, int n_in,
                              void* d_out, int out_size, void* d_ws, size_t ws_size,
                              hipStream_t stream) {
  (void)in_sizes; (void)n_in; (void)out_size; (void)ws_size;
  const float* x      = (const float*)d_in[0];
  const float* gate_w = (const float*)d_in[1];
  const float* w1     = (const float*)d_in[2];
  const float* b1     = (const float*)d_in[3];
  const float* w2     = (const float*)d_in[4];
  const float* b2     = (const float*)d_in[5];
  float* out = (float*)d_out;

  char* ws = (char*)d_ws;
  size_t off = 0;
  auto alloc = [&](size_t bytes) {
    char* p = ws + off;
    off += (bytes + 255) & ~(size_t)255;
    return p;
  };
  unsigned short* xb    = (unsigned short*)alloc((size_t)TOKENS * EMBD * 2);
  unsigned short* w1t   = (unsigned short*)alloc((size_t)NE * HID * EMBD * 2);
  unsigned short* w2t   = (unsigned short*)alloc((size_t)NE * EMBD * HID * 2);
  unsigned short* Hbuf  = (unsigned short*)alloc((size_t)(TOKENS * 2 + 128) * HID * 2);
  int*   token_list     = (int*)alloc((size_t)(TOKENS * 2 + 128) * 4);
  float* slot_w         = (float*)alloc((size_t)(TOKENS * 2 + 128) * 4);
  int*   idx2           = (int*)alloc((size_t)TOKENS * 2 * 4);
  float* wv             = (float*)alloc((size_t)TOKENS * 2 * 4);
  int*   ctrl           = (int*)alloc(32 * 4);

  k_convert_x<<<1024, 256, 0, stream>>>(x, xb, ctrl);
  k_transpose_bf16<<<dim3(HID / 64, EMBD / 64, NE), 256, 0, stream>>>(w1, w1t, EMBD, HID);
  k_transpose_bf16<<<dim3(EMBD / 64, HID / 64, NE), 256, 0, stream>>>(w2, w2t, HID, EMBD);
  k_gate<<<TOKENS, 256, 0, stream>>>(x, gate_w, out, idx2, wv, ctrl);
  k_scan<<<1, 64, 0, stream>>>(ctrl);
  k_assign<<<TOKENS / 256, 256, 0, stream>>>(idx2, wv, ctrl, token_list, slot_w);
  k_gemm1<<<dim3(HID / 128, TOKENS / 128, NE), 256, 0, stream>>>(xb, w1t, b1, ctrl, token_list, Hbuf);
  k_gemm2<<<dim3(EMBD / 128, TOKENS / 128, NE), 256, 0, stream>>>(Hbuf, w2t, b2, ctrl, token_list, slot_w, out);
}

// Round 2
// 714.008 us; speedup vs baseline: 1.0591x; 1.0591x over previous
//
#include <hip/hip_runtime.h>
#include <math.h>

#define TOKENS 4096
#define EMBD   1024
#define HID    4096
#define NE     8
#define SLOTC  8320   // padded slot capacity (8192 used)

typedef __attribute__((ext_vector_type(8))) short short8;
typedef __attribute__((ext_vector_type(4))) float f32x4;

#define GLOBAL_PTR(p) ((const __attribute__((address_space(1))) void*)(p))
#define LDS_PTR(p)    ((__attribute__((address_space(3))) void*)(p))

__device__ __forceinline__ unsigned short f2bf(float f) {
  unsigned int u = __float_as_uint(f);
  u += 0x7FFFu + ((u >> 16) & 1u);   // round-to-nearest-even
  return (unsigned short)(u >> 16);
}
__device__ __forceinline__ float bf2f(unsigned short h) {
  return __uint_as_float((unsigned int)h << 16);
}

// ---------- zero control block ----------
__global__ void k_zero_ctrl(int* __restrict__ ctrl) {
  if (threadIdx.x < 32) ctrl[threadIdx.x] = 0;
}

// ---------- fused gate + x fp32->bf16 convert. One wave per token. ----------
__global__ __launch_bounds__(256) void k_gate_cvt(const float* __restrict__ x,
                                                  const float* __restrict__ gw,
                                                  unsigned short* __restrict__ xb,
                                                  int* __restrict__ idx2,
                                                  float* __restrict__ wv,
                                                  int* __restrict__ ctrl) {
  int wave = threadIdx.x >> 6, lane = threadIdx.x & 63;
  int t = blockIdx.x * 4 + wave;
  const float4* xr = (const float4*)(x + (size_t)t * EMBD);   // 256 float4
  ushort4* xbr = (ushort4*)(xb + (size_t)t * EMBD);
  float acc[NE];
#pragma unroll
  for (int e = 0; e < NE; e++) acc[e] = 0.f;
#pragma unroll
  for (int ch = 0; ch < 4; ch++) {
    int i = ch * 64 + lane;
    float4 v = xr[i];
    ushort4 o;
    o.x = f2bf(v.x); o.y = f2bf(v.y); o.z = f2bf(v.z); o.w = f2bf(v.w);
    xbr[i] = o;
    int c = i * 4;
    const float* g0 = gw + (size_t)c * NE;
#pragma unroll
    for (int e = 0; e < NE; e++) acc[e] += v.x * g0[e];
#pragma unroll
    for (int e = 0; e < NE; e++) acc[e] += v.y * g0[NE + e];
#pragma unroll
    for (int e = 0; e < NE; e++) acc[e] += v.z * g0[2 * NE + e];
#pragma unroll
    for (int e = 0; e < NE; e++) acc[e] += v.w * g0[3 * NE + e];
  }
#pragma unroll
  for (int e = 0; e < NE; e++) {
#pragma unroll
    for (int off = 32; off > 0; off >>= 1) acc[e] += __shfl_down(acc[e], off);
  }
  if (lane == 0) {
    float best = -1e30f, second = -1e30f;
    int bi = 0, si = 0;
#pragma unroll
    for (int e = 0; e < NE; e++) {
      float l = acc[e];
      if (l > best) { second = best; si = bi; best = l; bi = e; }
      else if (l > second) { second = l; si = e; }
    }
    float b = expf(second - best);
    float w0 = 1.f / (1.f + b);
    float w1 = b / (1.f + b);
    idx2[2 * t] = bi; idx2[2 * t + 1] = si;
    wv[2 * t] = w0; wv[2 * t + 1] = w1;
    atomicAdd(&ctrl[bi], 1);
    atomicAdd(&ctrl[si], 1);
  }
}

// ---------- tiny scan ----------
__global__ void k_scan(int* __restrict__ ctrl) {
  if (threadIdx.x == 0) {
    int off = 0;
    for (int e = 0; e < NE; e++) { ctrl[8 + e] = off; off += ctrl[e]; }
    ctrl[16] = off;
  }
  if (threadIdx.x < NE) ctrl[17 + threadIdx.x] = 0;
}

// ---------- slot assignment (+ inverse map) ----------
__global__ __launch_bounds__(256) void k_assign(const int* __restrict__ idx2,
                                                const float* __restrict__ wv,
                                                int* __restrict__ ctrl,
                                                int* __restrict__ token_list,
                                                float* __restrict__ slot_w,
                                                int* __restrict__ tok2slot) {
  int t = blockIdx.x * 256 + threadIdx.x;
  if (t >= TOKENS) return;
#pragma unroll
  for (int k = 0; k < 2; k++) {
    int e = idx2[2 * t + k];
    int pos = atomicAdd(&ctrl[17 + e], 1);
    int slot = ctrl[8 + e] + pos;
    token_list[slot] = t;
    slot_w[slot] = wv[2 * t + k];
    tok2slot[2 * t + k] = slot;
  }
}

// ---------- transpose+convert: in [e][R][C] fp32 -> out [e][C][R] bf16 ----------
// float4 global reads -> LDS (stored transposed) -> ushort4 global stores.
__global__ __launch_bounds__(256) void k_trans(const float* __restrict__ in,
                                               unsigned short* __restrict__ out,
                                               int R, int C) {
  __shared__ unsigned short T[64 * 66];   // [col][row], pad 66
  int e = blockIdx.z;
  const float* ine = in + (size_t)e * R * C;
  unsigned short* oute = out + (size_t)e * R * C;
  int r0 = blockIdx.y * 64;
  int c0 = blockIdx.x * 64;
  int tid = threadIdx.x;
  {
    int c4 = tid & 15;          // float4 col chunk
    int rb = tid >> 4;          // 0..15
#pragma unroll
    for (int it = 0; it < 4; it++) {
      int r = rb + 16 * it;
      float4 v = *(const float4*)(ine + (size_t)(r0 + r) * C + c0 + 4 * c4);
      T[(4 * c4 + 0) * 66 + r] = f2bf(v.x);
      T[(4 * c4 + 1) * 66 + r] = f2bf(v.y);
      T[(4 * c4 + 2) * 66 + r] = f2bf(v.z);
      T[(4 * c4 + 3) * 66 + r] = f2bf(v.w);
    }
  }
  __syncthreads();
  {
    int rr4 = tid & 15;         // ushort4 chunk along output row
    int cq = tid >> 4;          // 0..15
#pragma unroll
    for (int it = 0; it < 4; it++) {
      int c = cq + 16 * it;     // output row (= input col)
      ushort4 o;
      o.x = T[c * 66 + 4 * rr4 + 0];
      o.y = T[c * 66 + 4 * rr4 + 1];
      o.z = T[c * 66 + 4 * rr4 + 2];
      o.w = T[c * 66 + 4 * rr4 + 3];
      *(ushort4*)(oute + (size_t)(c0 + c) * R + r0 + 4 * rr4) = o;
    }
  }
}

// ---------- GEMM1: H = gelu(gather(x) @ w1[e] + b1[e]) ----------
__global__ __launch_bounds__(256, 2) void k_gemm1(
    const unsigned short* __restrict__ xb,
    const unsigned short* __restrict__ w1t,
    const float* __restrict__ b1,
    const int* __restrict__ ctrl,
    const int* __restrict__ token_list,
    unsigned short* __restrict__ Hbuf) {
  int e = blockIdx.z;
  int cnt = ctrl[e];
  int m_base = blockIdx.y * 128;
  if (m_base >= cnt) return;
  int off_e = ctrl[8 + e];
  int nb = blockIdx.x * 128;
  int tid = threadIdx.x;
  int wave = tid >> 6, lane = tid & 63;

  __shared__ __align__(16) unsigned short As[128 * 32];
  __shared__ __align__(16) unsigned short Bs[128 * 32];

  int q0 = tid, q1 = 256 + tid;
  int rowA0 = q0 >> 2, ch0 = q0 & 3;
  int rowA1 = q1 >> 2, ch1 = q1 & 3;
  int tok0 = token_list[off_e + min(m_base + rowA0, cnt - 1)];
  int tok1 = token_list[off_e + min(m_base + rowA1, cnt - 1)];
  const unsigned short* srcA0 = xb + (size_t)tok0 * EMBD + ch0 * 8;
  const unsigned short* srcA1 = xb + (size_t)tok1 * EMBD + ch1 * 8;
  const unsigned short* wb = w1t + (size_t)e * HID * EMBD;
  const unsigned short* srcB0 = wb + (size_t)(nb + rowA0) * EMBD + ch0 * 8;
  const unsigned short* srcB1 = wb + (size_t)(nb + rowA1) * EMBD + ch1 * 8;
  char* AsB = (char*)As;
  char* BsB = (char*)Bs;

  f32x4 acc[4][4];
#pragma unroll
  for (int i = 0; i < 4; i++)
#pragma unroll
    for (int j = 0; j < 4; j++) acc[i][j] = (f32x4){0.f, 0.f, 0.f, 0.f};

  int wm = (wave >> 1) * 64, wn = (wave & 1) * 64;
  int q4 = lane >> 4, cc = lane & 15;

  for (int k0 = 0; k0 < EMBD; k0 += 32) {
    __builtin_amdgcn_global_load_lds(GLOBAL_PTR(srcA0 + k0), LDS_PTR(AsB + wave * 1024), 16, 0, 0);
    __builtin_amdgcn_global_load_lds(GLOBAL_PTR(srcA1 + k0), LDS_PTR(AsB + 4096 + wave * 1024), 16, 0, 0);
    __builtin_amdgcn_global_load_lds(GLOBAL_PTR(srcB0 + k0), LDS_PTR(BsB + wave * 1024), 16, 0, 0);
    __builtin_amdgcn_global_load_lds(GLOBAL_PTR(srcB1 + k0), LDS_PTR(BsB + 4096 + wave * 1024), 16, 0, 0);
    __syncthreads();
    short8 af[4], bfr[4];
#pragma unroll
    for (int i = 0; i < 4; i++)
      af[i] = *(const short8*)(As + (wm + i * 16 + cc) * 32 + q4 * 8);
#pragma unroll
    for (int j = 0; j < 4; j++)
      bfr[j] = *(const short8*)(Bs + (wn + j * 16 + cc) * 32 + q4 * 8);
#pragma unroll
    for (int i = 0; i < 4; i++)
#pragma unroll
      for (int j = 0; j < 4; j++)
        acc[i][j] = __builtin_amdgcn_mfma_f32_16x16x32_bf16(af[i], bfr[j], acc[i][j], 0, 0, 0);
    __syncthreads();
  }

  const float* b1e = b1 + (size_t)e * HID;
  float bias[4];
#pragma unroll
  for (int j = 0; j < 4; j++) bias[j] = b1e[nb + wn + j * 16 + cc];
#pragma unroll
  for (int i = 0; i < 4; i++) {
#pragma unroll
    for (int r = 0; r < 4; r++) {
      int m_loc = wm + i * 16 + q4 * 4 + r;
      int m = m_base + m_loc;
      if (m < cnt) {
        size_t hrow = (size_t)(off_e + m) * HID;
#pragma unroll
        for (int j = 0; j < 4; j++) {
          float v = acc[i][j][r] + bias[j];
          float g = 0.5f * v * (1.f + erff(v * 0.70710678118654752f));
          Hbuf[hrow + nb + wn + j * 16 + cc] = f2bf(g);
        }
      }
    }
  }
}

// ---------- GEMM2 (split-K=2): Yp[s][slot] = H[slot] @ w2[e][kslice] (raw partial) ----------
__global__ __launch_bounds__(256, 2) void k_gemm2(
    const unsigned short* __restrict__ Hbuf,
    const unsigned short* __restrict__ w2t,
    const int* __restrict__ ctrl,
    unsigned short* __restrict__ Yp) {
  int z = blockIdx.z;
  int e = z >> 1, s = z & 1;
  int cnt = ctrl[e];
  int m_base = blockIdx.y * 128;
  if (m_base >= cnt) return;
  int off_e = ctrl[8 + e];
  int nb = blockIdx.x * 128;
  int tid = threadIdx.x;
  int wave = tid >> 6, lane = tid & 63;

  __shared__ __align__(16) unsigned short As[128 * 32];
  __shared__ __align__(16) unsigned short Bs[128 * 32];

  int q0 = tid, q1 = 256 + tid;
  int rowA0 = q0 >> 2, ch0 = q0 & 3;
  int rowA1 = q1 >> 2, ch1 = q1 & 3;
  const unsigned short* srcA0 = Hbuf + (size_t)(off_e + m_base + rowA0) * HID + ch0 * 8;
  const unsigned short* srcA1 = Hbuf + (size_t)(off_e + m_base + rowA1) * HID + ch1 * 8;
  const unsigned short* wb = w2t + (size_t)e * EMBD * HID;
  const unsigned short* srcB0 = wb + (size_t)(nb + rowA0) * HID + ch0 * 8;
  const unsigned short* srcB1 = wb + (size_t)(nb + rowA1) * HID + ch1 * 8;
  char* AsB = (char*)As;
  char* BsB = (char*)Bs;

  f32x4 acc[4][4];
#pragma unroll
  for (int i = 0; i < 4; i++)
#pragma unroll
    for (int j = 0; j < 4; j++) acc[i][j] = (f32x4){0.f, 0.f, 0.f, 0.f};

  int wm = (wave >> 1) * 64, wn = (wave & 1) * 64;
  int q4 = lane >> 4, cc = lane & 15;

  int kbeg = s * (HID / 2), kend = kbeg + HID / 2;
  for (int k0 = kbeg; k0 < kend; k0 += 32) {
    __builtin_amdgcn_global_load_lds(GLOBAL_PTR(srcA0 + k0), LDS_PTR(AsB + wave * 1024), 16, 0, 0);
    __builtin_amdgcn_global_load_lds(GLOBAL_PTR(srcA1 + k0), LDS_PTR(AsB + 4096 + wave * 1024), 16, 0, 0);
    __builtin_amdgcn_global_load_lds(GLOBAL_PTR(srcB0 + k0), LDS_PTR(BsB + wave * 1024), 16, 0, 0);
    __builtin_amdgcn_global_load_lds(GLOBAL_PTR(srcB1 + k0), LDS_PTR(BsB + 4096 + wave * 1024), 16, 0, 0);
    __syncthreads();
    short8 af[4], bfr[4];
#pragma unroll
    for (int i = 0; i < 4; i++)
      af[i] = *(const short8*)(As + (wm + i * 16 + cc) * 32 + q4 * 8);
#pragma unroll
    for (int j = 0; j < 4; j++)
      bfr[j] = *(const short8*)(Bs + (wn + j * 16 + cc) * 32 + q4 * 8);
#pragma unroll
    for (int i = 0; i < 4; i++)
#pragma unroll
      for (int j = 0; j < 4; j++)
        acc[i][j] = __builtin_amdgcn_mfma_f32_16x16x32_bf16(af[i], bfr[j], acc[i][j], 0, 0, 0);
    __syncthreads();
  }

  unsigned short* Yps = Yp + (size_t)s * SLOTC * EMBD;
#pragma unroll
  for (int i = 0; i < 4; i++) {
#pragma unroll
    for (int r = 0; r < 4; r++) {
      int m_loc = wm + i * 16 + q4 * 4 + r;
      int m = m_base + m_loc;
      if (m < cnt) {
        size_t yrow = (size_t)(off_e + m) * EMBD;
#pragma unroll
        for (int j = 0; j < 4; j++)
          Yps[yrow + nb + wn + j * 16 + cc] = f2bf(acc[i][j][r]);
      }
    }
  }
}

// ---------- combine: out[t] = sum_k wv_k * (b2[e_k] + sum_s Yp[s][slot_k]) ----------
__global__ __launch_bounds__(256) void k_combine(const unsigned short* __restrict__ Yp,
                                                 const float* __restrict__ b2,
                                                 const int* __restrict__ idx2,
                                                 const float* __restrict__ wv,
                                                 const int* __restrict__ tok2slot,
                                                 float* __restrict__ out) {
  int t = blockIdx.x;
  int tid = threadIdx.x;
  int c = tid * 4;
  int e0 = idx2[2 * t], e1 = idx2[2 * t + 1];
  float w0 = wv[2 * t], w1 = wv[2 * t + 1];
  int s0 = tok2slot[2 * t], s1 = tok2slot[2 * t + 1];
  ushort4 p00 = *(const ushort4*)(Yp + ((size_t)0 * SLOTC + s0) * EMBD + c);
  ushort4 p01 = *(const ushort4*)(Yp + ((size_t)1 * SLOTC + s0) * EMBD + c);
  ushort4 p10 = *(const ushort4*)(Yp + ((size_t)0 * SLOTC + s1) * EMBD + c);
  ushort4 p11 = *(const ushort4*)(Yp + ((size_t)1 * SLOTC + s1) * EMBD + c);
  float4 b20 = *(const float4*)(b2 + (size_t)e0 * EMBD + c);
  float4 b21 = *(const float4*)(b2 + (size_t)e1 * EMBD + c);
  float4 r;
  r.x = w0 * (bf2f(p00.x) + bf2f(p01.x) + b20.x) + w1 * (bf2f(p10.x) + bf2f(p11.x) + b21.x);
  r.y = w0 * (bf2f(p00.y) + bf2f(p01.y) + b20.y) + w1 * (bf2f(p10.y) + bf2f(p11.y) + b21.y);
  r.z = w0 * (bf2f(p00.z) + bf2f(p01.z) + b20.z) + w1 * (bf2f(p10.z) + bf2f(p11.z) + b21.z);
  r.w = w0 * (bf2f(p00.w) + bf2f(p01.w) + b20.w) + w1 * (bf2f(p10.w) + bf2f(p11.w) + b21.w);
  *(float4*)(out + (size_t)t * EMBD + c) = r;
}

extern "C" void kernel_launch(void* const* d_in, const int* in_sizes, int n_in,
                              void* d_out, int out_size, void* d_ws, size_t ws_size,
                              hipStream_t stream) {
  (void)in_sizes; (void)n_in; (void)out_size; (void)ws_size;
  const float* x      = (const float*)d_in[0];
  const float* gate_w = (const float*)d_in[1];
  const float* w1     = (const float*)d_in[2];
  const float* b1     = (const float*)d_in[3];
  const float* w2     = (const float*)d_in[4];
  const float* b2     = (const float*)d_in[5];
  float* out = (float*)d_out;

  char* ws = (char*)d_ws;
  size_t off = 0;
  auto alloc = [&](size_t bytes) {
    char* p = ws + off;
    off += (bytes + 255) & ~(size_t)255;
    return p;
  };
  unsigned short* xb    = (unsigned short*)alloc((size_t)TOKENS * EMBD * 2);
  unsigned short* w1t   = (unsigned short*)alloc((size_t)NE * HID * EMBD * 2);
  unsigned short* w2t   = (unsigned short*)alloc((size_t)NE * EMBD * HID * 2);
  unsigned short* Hbuf  = (unsigned short*)alloc((size_t)SLOTC * HID * 2);
  unsigned short* Yp    = (unsigned short*)alloc((size_t)2 * SLOTC * EMBD * 2);
  int*   token_list     = (int*)alloc((size_t)SLOTC * 4);
  float* slot_w         = (float*)alloc((size_t)SLOTC * 4);
  int*   idx2           = (int*)alloc((size_t)TOKENS * 2 * 4);
  float* wv             = (float*)alloc((size_t)TOKENS * 2 * 4);
  int*   tok2slot       = (int*)alloc((size_t)TOKENS * 2 * 4);
  int*   ctrl           = (int*)alloc(32 * 4);

  k_zero_ctrl<<<1, 64, 0, stream>>>(ctrl);
  k_gate_cvt<<<TOKENS / 4, 256, 0, stream>>>(x, gate_w, xb, idx2, wv, ctrl);
  k_scan<<<1, 64, 0, stream>>>(ctrl);
  k_assign<<<TOKENS / 256, 256, 0, stream>>>(idx2, wv, ctrl, token_list, slot_w, tok2slot);
  k_trans<<<dim3(HID / 64, EMBD / 64, NE), 256, 0, stream>>>(w1, w1t, EMBD, HID);
  k_trans<<<dim3(EMBD / 64, HID / 64, NE), 256, 0, stream>>>(w2, w2t, HID, EMBD);
  k_gemm1<<<dim3(HID / 128, TOKENS / 128, NE), 256, 0, stream>>>(xb, w1t, b1, ctrl, token_list, Hbuf);
  k_gemm2<<<dim3(EMBD / 128, TOKENS / 128, NE * 2), 256, 0, stream>>>(Hbuf, w2t, ctrl, Yp);
  k_combine<<<TOKENS, 256, 0, stream>>>(Yp, b2, idx2, wv, tok2slot, out);
}

// Round 3
// 687.647 us; speedup vs baseline: 1.0997x; 1.0383x over previous
//
#include <hip/hip_runtime.h>
#include <math.h>

#define TOKENS 4096
#define EMBD   1024
#define HID    4096
#define NE     8
#define SLOTC  8320   // padded slot capacity (8192 used)

typedef __attribute__((ext_vector_type(8))) short short8;
typedef __attribute__((ext_vector_type(4))) float f32x4;

#define GLOBAL_PTR(p) ((const __attribute__((address_space(1))) void*)(p))
#define LDS_PTR(p)    ((__attribute__((address_space(3))) void*)(p))

// LDS fragment address with XOR chunk swizzle (shorts). Chunk q lives at
// granule q ^ ((row>>1)&3) -> 16-lane read phases hit 8 bank-quads x2 = free.
#define SWZ(row, q) ((row) * 32 + (((q) ^ (((row) >> 1) & 3)) * 8))

__device__ __forceinline__ unsigned short f2bf(float f) {
  unsigned int u = __float_as_uint(f);
  u += 0x7FFFu + ((u >> 16) & 1u);   // round-to-nearest-even
  return (unsigned short)(u >> 16);
}
__device__ __forceinline__ float bf2f(unsigned short h) {
  return __uint_as_float((unsigned int)h << 16);
}

// exact-GELU via Abramowitz-Stegun 7.1.26 erf (|eps| < 1.5e-7), ~12 VALU ops
__device__ __forceinline__ float fast_gelu(float v) {
  float u = fabsf(v) * 0.70710678118654752f;
  float t = 1.0f / (1.0f + 0.3275911f * u);
  float poly = ((((1.061405429f * t - 1.453152027f) * t + 1.421413741f) * t
                 - 0.284496736f) * t + 0.254829592f) * t;
  float erf_abs = 1.0f - poly * __expf(-u * u);
  float er = (v < 0.0f) ? -erf_abs : erf_abs;
  return 0.5f * v * (1.0f + er);
}

// ---------- zero control block ----------
__global__ void k_zero_ctrl(int* __restrict__ ctrl) {
  if (threadIdx.x < 32) ctrl[threadIdx.x] = 0;
}

// ---------- fused gate + x fp32->bf16 convert. One wave per token. ----------
__global__ __launch_bounds__(256) void k_gate_cvt(const float* __restrict__ x,
                                                  const float* __restrict__ gw,
                                                  unsigned short* __restrict__ xb,
                                                  int* __restrict__ idx2,
                                                  float* __restrict__ wv,
                                                  int* __restrict__ ctrl) {
  int wave = threadIdx.x >> 6, lane = threadIdx.x & 63;
  int t = blockIdx.x * 4 + wave;
  const float4* xr = (const float4*)(x + (size_t)t * EMBD);   // 256 float4
  ushort4* xbr = (ushort4*)(xb + (size_t)t * EMBD);
  float acc[NE];
#pragma unroll
  for (int e = 0; e < NE; e++) acc[e] = 0.f;
#pragma unroll
  for (int ch = 0; ch < 4; ch++) {
    int i = ch * 64 + lane;
    float4 v = xr[i];
    ushort4 o;
    o.x = f2bf(v.x); o.y = f2bf(v.y); o.z = f2bf(v.z); o.w = f2bf(v.w);
    xbr[i] = o;
    int c = i * 4;
    const float* g0 = gw + (size_t)c * NE;
#pragma unroll
    for (int e = 0; e < NE; e++) acc[e] += v.x * g0[e];
#pragma unroll
    for (int e = 0; e < NE; e++) acc[e] += v.y * g0[NE + e];
#pragma unroll
    for (int e = 0; e < NE; e++) acc[e] += v.z * g0[2 * NE + e];
#pragma unroll
    for (int e = 0; e < NE; e++) acc[e] += v.w * g0[3 * NE + e];
  }
#pragma unroll
  for (int e = 0; e < NE; e++) {
#pragma unroll
    for (int off = 32; off > 0; off >>= 1) acc[e] += __shfl_down(acc[e], off);
  }
  if (lane == 0) {
    float best = -1e30f, second = -1e30f;
    int bi = 0, si = 0;
#pragma unroll
    for (int e = 0; e < NE; e++) {
      float l = acc[e];
      if (l > best) { second = best; si = bi; best = l; bi = e; }
      else if (l > second) { second = l; si = e; }
    }
    float b = expf(second - best);
    float w0 = 1.f / (1.f + b);
    float w1 = b / (1.f + b);
    idx2[2 * t] = bi; idx2[2 * t + 1] = si;
    wv[2 * t] = w0; wv[2 * t + 1] = w1;
    atomicAdd(&ctrl[bi], 1);
    atomicAdd(&ctrl[si], 1);
  }
}

// ---------- tiny scan ----------
__global__ void k_scan(int* __restrict__ ctrl) {
  if (threadIdx.x == 0) {
    int off = 0;
    for (int e = 0; e < NE; e++) { ctrl[8 + e] = off; off += ctrl[e]; }
    ctrl[16] = off;
  }
  if (threadIdx.x < NE) ctrl[17 + threadIdx.x] = 0;
}

// ---------- slot assignment (+ inverse map) ----------
__global__ __launch_bounds__(256) void k_assign(const int* __restrict__ idx2,
                                                const float* __restrict__ wv,
                                                int* __restrict__ ctrl,
                                                int* __restrict__ token_list,
                                                float* __restrict__ slot_w,
                                                int* __restrict__ tok2slot) {
  int t = blockIdx.x * 256 + threadIdx.x;
  if (t >= TOKENS) return;
#pragma unroll
  for (int k = 0; k < 2; k++) {
    int e = idx2[2 * t + k];
    int pos = atomicAdd(&ctrl[17 + e], 1);
    int slot = ctrl[8 + e] + pos;
    token_list[slot] = t;
    slot_w[slot] = wv[2 * t + k];
    tok2slot[2 * t + k] = slot;
  }
}

// ---------- transpose+convert: in [e][R][C] fp32 -> out [e][C][R] bf16 ----------
__global__ __launch_bounds__(256) void k_trans(const float* __restrict__ in,
                                               unsigned short* __restrict__ out,
                                               int R, int C) {
  __shared__ unsigned short T[64 * 66];   // [col][row], pad 66
  int e = blockIdx.z;
  const float* ine = in + (size_t)e * R * C;
  unsigned short* oute = out + (size_t)e * R * C;
  int r0 = blockIdx.y * 64;
  int c0 = blockIdx.x * 64;
  int tid = threadIdx.x;
  {
    int c4 = tid & 15;          // float4 col chunk
    int rb = tid >> 4;          // 0..15
#pragma unroll
    for (int it = 0; it < 4; it++) {
      int r = rb + 16 * it;
      float4 v = *(const float4*)(ine + (size_t)(r0 + r) * C + c0 + 4 * c4);
      T[(4 * c4 + 0) * 66 + r] = f2bf(v.x);
      T[(4 * c4 + 1) * 66 + r] = f2bf(v.y);
      T[(4 * c4 + 2) * 66 + r] = f2bf(v.z);
      T[(4 * c4 + 3) * 66 + r] = f2bf(v.w);
    }
  }
  __syncthreads();
  {
    int rr = tid & 7;           // 16B chunk along output row
    int cq = tid >> 3;          // 0..31
#pragma unroll
    for (int it = 0; it < 2; it++) {
      int c = cq + 32 * it;     // output row (= input col)
      short8 o;
#pragma unroll
      for (int k = 0; k < 8; k++) o[k] = (short)T[c * 66 + 8 * rr + k];
      *(short8*)(oute + (size_t)(c0 + c) * R + r0 + 8 * rr) = o;
    }
  }
}

// ---------- GEMM1: H = gelu(gather(x) @ w1[e] + b1[e]) ----------
// 1D grid 8192: e = h&7 (XCD-keyed), j = h>>3, n_blk = j&31, m_blk = j>>5.
__global__ __launch_bounds__(256, 2) void k_gemm1(
    const unsigned short* __restrict__ xb,
    const unsigned short* __restrict__ w1t,
    const float* __restrict__ b1,
    const int* __restrict__ ctrl,
    const int* __restrict__ token_list,
    unsigned short* __restrict__ Hbuf) {
  int h = blockIdx.x;
  int e = h & 7;
  int j = h >> 3;
  int nb = (j & 31) * 128;
  int m_base = (j >> 5) * 128;
  int cnt = ctrl[e];
  if (m_base >= cnt) return;
  int off_e = ctrl[8 + e];
  int tid = threadIdx.x;
  int wave = tid >> 6, lane = tid & 63;

  __shared__ __align__(16) unsigned short As[128 * 32];
  __shared__ __align__(16) unsigned short Bs[128 * 32];

  // staging: lane covers 16B; LDS addr = tid*16 (+4096 for 2nd half).
  // chunk swizzle: lane at stored-chunk (tid&3) fetches global chunk chS.
  int chS = (tid & 3) ^ ((tid >> 3) & 3);
  int rowA0 = tid >> 2;            // rows 0..63
  int rowA1 = 64 + (tid >> 2);     // rows 64..127
  int tok0 = token_list[off_e + min(m_base + rowA0, cnt - 1)];
  int tok1 = token_list[off_e + min(m_base + rowA1, cnt - 1)];
  const unsigned short* srcA0 = xb + (size_t)tok0 * EMBD + chS * 8;
  const unsigned short* srcA1 = xb + (size_t)tok1 * EMBD + chS * 8;
  const unsigned short* wb = w1t + (size_t)e * HID * EMBD;
  const unsigned short* srcB0 = wb + (size_t)(nb + rowA0) * EMBD + chS * 8;
  const unsigned short* srcB1 = wb + (size_t)(nb + rowA1) * EMBD + chS * 8;
  char* AsB = (char*)As;
  char* BsB = (char*)Bs;

  f32x4 acc[4][4];
#pragma unroll
  for (int i = 0; i < 4; i++)
#pragma unroll
    for (int j2 = 0; j2 < 4; j2++) acc[i][j2] = (f32x4){0.f, 0.f, 0.f, 0.f};

  int wm = (wave >> 1) * 64, wn = (wave & 1) * 64;
  int q4 = lane >> 4, cc = lane & 15;

  for (int k0 = 0; k0 < EMBD; k0 += 32) {
    __builtin_amdgcn_global_load_lds(GLOBAL_PTR(srcA0 + k0), LDS_PTR(AsB + wave * 1024), 16, 0, 0);
    __builtin_amdgcn_global_load_lds(GLOBAL_PTR(srcA1 + k0), LDS_PTR(AsB + 4096 + wave * 1024), 16, 0, 0);
    __builtin_amdgcn_global_load_lds(GLOBAL_PTR(srcB0 + k0), LDS_PTR(BsB + wave * 1024), 16, 0, 0);
    __builtin_amdgcn_global_load_lds(GLOBAL_PTR(srcB1 + k0), LDS_PTR(BsB + 4096 + wave * 1024), 16, 0, 0);
    __syncthreads();
    short8 af[4], bfr[4];
#pragma unroll
    for (int i = 0; i < 4; i++)
      af[i] = *(const short8*)(As + SWZ(wm + i * 16 + cc, q4));
#pragma unroll
    for (int j2 = 0; j2 < 4; j2++)
      bfr[j2] = *(const short8*)(Bs + SWZ(wn + j2 * 16 + cc, q4));
#pragma unroll
    for (int i = 0; i < 4; i++)
#pragma unroll
      for (int j2 = 0; j2 < 4; j2++)
        acc[i][j2] = __builtin_amdgcn_mfma_f32_16x16x32_bf16(af[i], bfr[j2], acc[i][j2], 0, 0, 0);
    __syncthreads();
  }

  const float* b1e = b1 + (size_t)e * HID;
  float bias[4];
#pragma unroll
  for (int j2 = 0; j2 < 4; j2++) bias[j2] = b1e[nb + wn + j2 * 16 + cc];
#pragma unroll
  for (int i = 0; i < 4; i++) {
#pragma unroll
    for (int r = 0; r < 4; r++) {
      int m_loc = wm + i * 16 + q4 * 4 + r;
      int m = m_base + m_loc;
      if (m < cnt) {
        size_t hrow = (size_t)(off_e + m) * HID;
#pragma unroll
        for (int j2 = 0; j2 < 4; j2++)
          Hbuf[hrow + nb + wn + j2 * 16 + cc] = f2bf(fast_gelu(acc[i][j2][r] + bias[j2]));
      }
    }
  }
}

// ---------- GEMM2 (split-K=2): Yp[s][slot] = H[slot] @ w2[e][kslice] ----------
// 1D grid 4096: e = h&7 (XCD-keyed), s = (h>>3)&1, rem = h>>4, m = rem>>3, n = rem&7.
__global__ __launch_bounds__(256, 2) void k_gemm2(
    const unsigned short* __restrict__ Hbuf,
    const unsigned short* __restrict__ w2t,
    const int* __restrict__ ctrl,
    unsigned short* __restrict__ Yp) {
  int h = blockIdx.x;
  int e = h & 7;
  int s = (h >> 3) & 1;
  int rem = h >> 4;
  int m_base = (rem >> 3) * 128;
  int nb = (rem & 7) * 128;
  int cnt = ctrl[e];
  if (m_base >= cnt) return;
  int off_e = ctrl[8 + e];
  int tid = threadIdx.x;
  int wave = tid >> 6, lane = tid & 63;

  __shared__ __align__(16) unsigned short As[128 * 32];
  __shared__ __align__(16) unsigned short Bs[128 * 32];

  int chS = (tid & 3) ^ ((tid >> 3) & 3);
  int rowA0 = tid >> 2;
  int rowA1 = 64 + (tid >> 2);
  const unsigned short* srcA0 = Hbuf + (size_t)(off_e + m_base + rowA0) * HID + chS * 8;
  const unsigned short* srcA1 = Hbuf + (size_t)(off_e + m_base + rowA1) * HID + chS * 8;
  const unsigned short* wb = w2t + (size_t)e * EMBD * HID;
  const unsigned short* srcB0 = wb + (size_t)(nb + rowA0) * HID + chS * 8;
  const unsigned short* srcB1 = wb + (size_t)(nb + rowA1) * HID + chS * 8;
  char* AsB = (char*)As;
  char* BsB = (char*)Bs;

  f32x4 acc[4][4];
#pragma unroll
  for (int i = 0; i < 4; i++)
#pragma unroll
    for (int j2 = 0; j2 < 4; j2++) acc[i][j2] = (f32x4){0.f, 0.f, 0.f, 0.f};

  int wm = (wave >> 1) * 64, wn = (wave & 1) * 64;
  int q4 = lane >> 4, cc = lane & 15;

  int kbeg = s * (HID / 2), kend = kbeg + HID / 2;
  for (int k0 = kbeg; k0 < kend; k0 += 32) {
    __builtin_amdgcn_global_load_lds(GLOBAL_PTR(srcA0 + k0), LDS_PTR(AsB + wave * 1024), 16, 0, 0);
    __builtin_amdgcn_global_load_lds(GLOBAL_PTR(srcA1 + k0), LDS_PTR(AsB + 4096 + wave * 1024), 16, 0, 0);
    __builtin_amdgcn_global_load_lds(GLOBAL_PTR(srcB0 + k0), LDS_PTR(BsB + wave * 1024), 16, 0, 0);
    __builtin_amdgcn_global_load_lds(GLOBAL_PTR(srcB1 + k0), LDS_PTR(BsB + 4096 + wave * 1024), 16, 0, 0);
    __syncthreads();
    short8 af[4], bfr[4];
#pragma unroll
    for (int i = 0; i < 4; i++)
      af[i] = *(const short8*)(As + SWZ(wm + i * 16 + cc, q4));
#pragma unroll
    for (int j2 = 0; j2 < 4; j2++)
      bfr[j2] = *(const short8*)(Bs + SWZ(wn + j2 * 16 + cc, q4));
#pragma unroll
    for (int i = 0; i < 4; i++)
#pragma unroll
      for (int j2 = 0; j2 < 4; j2++)
        acc[i][j2] = __builtin_amdgcn_mfma_f32_16x16x32_bf16(af[i], bfr[j2], acc[i][j2], 0, 0, 0);
    __syncthreads();
  }

  unsigned short* Yps = Yp + (size_t)s * SLOTC * EMBD;
#pragma unroll
  for (int i = 0; i < 4; i++) {
#pragma unroll
    for (int r = 0; r < 4; r++) {
      int m_loc = wm + i * 16 + q4 * 4 + r;
      int m = m_base + m_loc;
      if (m < cnt) {
        size_t yrow = (size_t)(off_e + m) * EMBD;
#pragma unroll
        for (int j2 = 0; j2 < 4; j2++)
          Yps[yrow + nb + wn + j2 * 16 + cc] = f2bf(acc[i][j2][r]);
      }
    }
  }
}

// ---------- combine: out[t] = sum_k wv_k * (b2[e_k] + sum_s Yp[s][slot_k]) ----------
__global__ __launch_bounds__(256) void k_combine(const unsigned short* __restrict__ Yp,
                                                 const float* __restrict__ b2,
                                                 const int* __restrict__ idx2,
                                                 const float* __restrict__ wv,
                                                 const int* __restrict__ tok2slot,
                                                 float* __restrict__ out) {
  int t = blockIdx.x;
  int tid = threadIdx.x;
  int c = tid * 4;
  int e0 = idx2[2 * t], e1 = idx2[2 * t + 1];
  float w0 = wv[2 * t], w1 = wv[2 * t + 1];
  int s0 = tok2slot[2 * t], s1 = tok2slot[2 * t + 1];
  ushort4 p00 = *(const ushort4*)(Yp + ((size_t)0 * SLOTC + s0) * EMBD + c);
  ushort4 p01 = *(const ushort4*)(Yp + ((size_t)1 * SLOTC + s0) * EMBD + c);
  ushort4 p10 = *(const ushort4*)(Yp + ((size_t)0 * SLOTC + s1) * EMBD + c);
  ushort4 p11 = *(const ushort4*)(Yp + ((size_t)1 * SLOTC + s1) * EMBD + c);
  float4 b20 = *(const float4*)(b2 + (size_t)e0 * EMBD + c);
  float4 b21 = *(const float4*)(b2 + (size_t)e1 * EMBD + c);
  float4 r;
  r.x = w0 * (bf2f(p00.x) + bf2f(p01.x) + b20.x) + w1 * (bf2f(p10.x) + bf2f(p11.x) + b21.x);
  r.y = w0 * (bf2f(p00.y) + bf2f(p01.y) + b20.y) + w1 * (bf2f(p10.y) + bf2f(p11.y) + b21.y);
  r.z = w0 * (bf2f(p00.z) + bf2f(p01.z) + b20.z) + w1 * (bf2f(p10.z) + bf2f(p11.z) + b21.z);
  r.w = w0 * (bf2f(p00.w) + bf2f(p01.w) + b20.w) + w1 * (bf2f(p10.w) + bf2f(p11.w) + b21.w);
  *(float4*)(out + (size_t)t * EMBD + c) = r;
}

extern "C" void kernel_launch(void* const* d_in, const int* in_sizes, int n_in,
                              void* d_out, int out_size, void* d_ws, size_t ws_size,
                              hipStream_t stream) {
  (void)in_sizes; (void)n_in; (void)out_size; (void)ws_size;
  const float* x      = (const float*)d_in[0];
  const float* gate_w = (const float*)d_in[1];
  const float* w1     = (const float*)d_in[2];
  const float* b1     = (const float*)d_in[3];
  const float* w2     = (const float*)d_in[4];
  const float* b2     = (const float*)d_in[5];
  float* out = (float*)d_out;

  char* ws = (char*)d_ws;
  size_t off = 0;
  auto alloc = [&](size_t bytes) {
    char* p = ws + off;
    off += (bytes + 255) & ~(size_t)255;
    return p;
  };
  unsigned short* xb    = (unsigned short*)alloc((size_t)TOKENS * EMBD * 2);
  unsigned short* w1t   = (unsigned short*)alloc((size_t)NE * HID * EMBD * 2);
  unsigned short* w2t   = (unsigned short*)alloc((size_t)NE * EMBD * HID * 2);
  unsigned short* Hbuf  = (unsigned short*)alloc((size_t)SLOTC * HID * 2);
  unsigned short* Yp    = (unsigned short*)alloc((size_t)2 * SLOTC * EMBD * 2);
  int*   token_list     = (int*)alloc((size_t)SLOTC * 4);
  float* slot_w         = (float*)alloc((size_t)SLOTC * 4);
  int*   idx2           = (int*)alloc((size_t)TOKENS * 2 * 4);
  float* wv             = (float*)alloc((size_t)TOKENS * 2 * 4);
  int*   tok2slot       = (int*)alloc((size_t)TOKENS * 2 * 4);
  int*   ctrl           = (int*)alloc(32 * 4);

  k_zero_ctrl<<<1, 64, 0, stream>>>(ctrl);
  k_gate_cvt<<<TOKENS / 4, 256, 0, stream>>>(x, gate_w, xb, idx2, wv, ctrl);
  k_scan<<<1, 64, 0, stream>>>(ctrl);
  k_assign<<<TOKENS / 256, 256, 0, stream>>>(idx2, wv, ctrl, token_list, slot_w, tok2slot);
  k_trans<<<dim3(HID / 64, EMBD / 64, NE), 256, 0, stream>>>(w1, w1t, EMBD, HID);
  k_trans<<<dim3(EMBD / 64, HID / 64, NE), 256, 0, stream>>>(w2, w2t, HID, EMBD);
  k_gemm1<<<8192, 256, 0, stream>>>(xb, w1t, b1, ctrl, token_list, Hbuf);
  k_gemm2<<<4096, 256, 0, stream>>>(Hbuf, w2t, ctrl, Yp);
  k_combine<<<TOKENS, 256, 0, stream>>>(Yp, b2, idx2, wv, tok2slot, out);
}